// Round 14
// baseline (1887.133 us; speedup 1.0000x reference)
//
#include <hip/hip_runtime.h>

#define NN 2048      // points
#define NB 16        // batch
#define KK 20        // k neighbors
#define EPSF 1e-5f

typedef unsigned long long ull;
typedef _Float16 v8h __attribute__((ext_vector_type(8)));
typedef float v4f __attribute__((ext_vector_type(4)));

__device__ __forceinline__ float shflx_f(float v, int m) { return __shfl_xor(v, m, 64); }
__device__ __forceinline__ ull shflx_u64(ull v, int m) {
  int lo = __shfl_xor((int)(unsigned)v, m, 64);
  int hi = __shfl_xor((int)(unsigned)(v >> 32), m, 64);
  return (((ull)(unsigned)hi) << 32) | (unsigned)lo;
}
__device__ __forceinline__ ull packkey(float s, int n) {
  unsigned u = __float_as_uint(s);
  u = (u & 0x80000000u) ? ~u : (u | 0x80000000u);
  return (((ull)u) << 32) | (unsigned)(2047 - n);   // ties -> lowest index wins under max
}

// ---------------- prep: x[C][N] fp32 -> fragment-ready f16 hi/lo [n][Cp] + xx ----
__global__ __launch_bounds__(256) void prep_kernel(const float* __restrict__ x,
    _Float16* __restrict__ xh, _Float16* __restrict__ xl, float* __restrict__ xx,
    int C, int KB, long bstride)
{
  const int b = blockIdx.y;
  const int n = blockIdx.x * 256 + threadIdx.x;
  const float* xb = x + (size_t)b * bstride;
  const int Cp = KB * 32;
  _Float16* ph = xh + ((size_t)b * NN + n) * Cp;
  _Float16* pl = xl + ((size_t)b * NN + n) * Cp;
  float s = 0.f;
  for (int kb = 0; kb < KB; kb++) {
    for (int g = 0; g < 4; g++) {
      v8h hv, lv;
#pragma unroll
      for (int j = 0; j < 8; j++) {
        int c = kb * 32 + g * 8 + j;
        float v = (c < C) ? xb[(size_t)c * NN + n] : 0.f;
        _Float16 h = (_Float16)v;
        hv[j] = h;
        lv[j] = (_Float16)(v - (float)h);
        s = fmaf(v, v, s);
      }
      *(v8h*)(ph + kb * 32 + g * 8) = hv;
      *(v8h*)(pl + kb * 32 + g * 8) = lv;
    }
  }
  xx[b * NN + n] = s;
}

// ---------------- tile scorer: 64 queries (4 A-tiles) x 16 candidates ----------
template<int KB>
__device__ __forceinline__ void tile_scores(const v8h (&Bh)[KB], const v8h (&Bl)[KB],
    const v8h (&Ah)[4][KB], const v8h (&Al)[4][KB], float xv, v4f (&out)[4])
{
#pragma unroll
  for (int a = 0; a < 4; a++) {
    v4f a0 = {0.f, 0.f, 0.f, 0.f};
    v4f a1 = {0.f, 0.f, 0.f, 0.f};
#pragma unroll
    for (int kb = 0; kb < KB; kb++) {
      v4f& acc = (kb & 1) ? a1 : a0;
      acc = __builtin_amdgcn_mfma_f32_16x16x32_f16(Ah[a][kb], Bh[kb], acc, 0, 0, 0);
      acc = __builtin_amdgcn_mfma_f32_16x16x32_f16(Ah[a][kb], Bl[kb], acc, 0, 0, 0);
      acc = __builtin_amdgcn_mfma_f32_16x16x32_f16(Al[a][kb], Bh[kb], acc, 0, 0, 0);
    }
    v4f s = a0 + a1;
#pragma unroll
    for (int j = 0; j < 4; j++) out[a][j] = s[j] - 0.5f * xv;
  }
}

// ---------------- kNN stage 1: 64 q/wave, 2 chunks, 2-deep ring (proven 209us) --
template<int KB>
__global__ __launch_bounds__(256, 1) void knn2(
    const _Float16* __restrict__ xh, const _Float16* __restrict__ xl,
    const float* __restrict__ xxg, ull* __restrict__ slistG, int* __restrict__ cntG)
{
  __shared__ float gmL[256][33];
  __shared__ float tauL[256];
  __shared__ int scnt[256];

  const int t = threadIdx.x;
  const int lane = t & 63;
  const int wave = t >> 6;
  const int col = lane & 15;
  const int quad = lane >> 4;
  const int quad8 = quad * 8;
  const int b = blockIdx.x >> 1;
  const int chunk = blockIdx.x & 1;
  const int qg = blockIdx.y;
  const int Cp = KB * 32;
  const int cb = chunk * 1024;
  const _Float16* xhb = xh + (size_t)b * NN * Cp;
  const _Float16* xlb = xl + (size_t)b * NN * Cp;
  const float* xxb = xxg + b * NN;

  v8h Ah[4][KB], Al[4][KB];
  const int qw = qg * 256 + wave * 64;
#pragma unroll
  for (int a = 0; a < 4; a++) {
    const _Float16* pa = xhb + (size_t)(qw + a * 16 + col) * Cp + quad8;
    const _Float16* pb = xlb + (size_t)(qw + a * 16 + col) * Cp + quad8;
#pragma unroll
    for (int kb = 0; kb < KB; kb++) {
      Ah[a][kb] = *(const v8h*)(pa + kb * 32);
      Al[a][kb] = *(const v8h*)(pb + kb * 32);
    }
  }

  v8h Bh[2][KB], Bl[2][KB];
  float xvb[2];
  auto loadB = [&](int slot, int tt) {
    int t2 = tt < 63 ? tt : 63;
    int n = cb + t2 * 16 + col;
    const _Float16* pb = xhb + (size_t)n * Cp + quad8;
    const _Float16* pl = xlb + (size_t)n * Cp + quad8;
#pragma unroll
    for (int kb = 0; kb < KB; kb++) {
      Bh[slot][kb] = *(const v8h*)(pb + kb * 32);
      Bl[slot][kb] = *(const v8h*)(pl + kb * 32);
    }
    xvb[slot] = xxb[n];
  };

  // ---- pass 1: group maxima (16 cols x 2 tile-parities = 32 groups/query) ----
  float gm[4][8];
#pragma unroll
  for (int a = 0; a < 4; a++)
#pragma unroll
    for (int j = 0; j < 8; j++) gm[a][j] = -3.4e38f;

  loadB(0, 0);
  for (int tt = 0; tt < 64; tt += 2) {
    loadB(1, tt + 1);
    {
      v4f out[4];
      tile_scores<KB>(Bh[0], Bl[0], Ah, Al, xvb[0], out);
#pragma unroll
      for (int a = 0; a < 4; a++)
#pragma unroll
        for (int j = 0; j < 4; j++) gm[a][j * 2] = fmaxf(gm[a][j * 2], out[a][j]);
    }
    loadB(0, tt + 2);
    {
      v4f out[4];
      tile_scores<KB>(Bh[1], Bl[1], Ah, Al, xvb[1], out);
#pragma unroll
      for (int a = 0; a < 4; a++)
#pragma unroll
        for (int j = 0; j < 4; j++) gm[a][j * 2 + 1] = fmaxf(gm[a][j * 2 + 1], out[a][j]);
    }
  }

#pragma unroll
  for (int a = 0; a < 4; a++)
#pragma unroll
    for (int j = 0; j < 4; j++) {
      int qi = wave * 64 + a * 16 + quad * 4 + j;
      gmL[qi][col * 2 + 0] = gm[a][j * 2 + 0];
      gmL[qi][col * 2 + 1] = gm[a][j * 2 + 1];
    }
  scnt[t] = 0;
  asm volatile("s_waitcnt lgkmcnt(0)" ::: "memory");

  // tau = rank-19 of 32 group maxima (provably <= true 20th score of the chunk)
  for (int r = 0; r < 32; r++) {
    const int q = wave * 64 + r * 2 + (lane >> 5);
    const int idx = lane & 31;
    float v = gmL[q][idx];
#pragma unroll
    for (int kk = 2; kk <= 32; kk <<= 1) {
#pragma unroll
      for (int m = kk >> 1; m >= 1; m >>= 1) {
        float o = shflx_f(v, m);
        bool keepmax = ((idx & kk) == 0) == ((idx & m) == 0);
        v = keepmax ? fmaxf(v, o) : fminf(v, o);
      }
    }
    if (idx == 19) tauL[q] = v;
  }
  asm volatile("s_waitcnt lgkmcnt(0)" ::: "memory");

  float tq[4][4];
#pragma unroll
  for (int a = 0; a < 4; a++)
#pragma unroll
    for (int j = 0; j < 4; j++) tq[a][j] = tauL[wave * 64 + a * 16 + quad * 4 + j];

  // ---- pass 2: bitwise-identical rescore, compact survivors >= tau ----
  ull* slB = slistG + (((size_t)b * NN + qg * 256) * 2 + chunk) * 64;
  loadB(0, 0);
  for (int tt = 0; tt < 64; tt += 2) {
    loadB(1, tt + 1);
    for (int s = 0; s < 2; s++) {
      v4f out[4];
      tile_scores<KB>(s ? Bh[1] : Bh[0], s ? Bl[1] : Bl[0], Ah, Al, xvb[s], out);
      int n = cb + (tt + s) * 16 + col;
#pragma unroll
      for (int a = 0; a < 4; a++)
#pragma unroll
        for (int j = 0; j < 4; j++) {
          float sc = out[a][j];
          if (sc >= tq[a][j]) {
            int qi = wave * 64 + a * 16 + quad * 4 + j;
            int pos = atomicAdd(&scnt[qi], 1);
            if (pos < 64) slB[(size_t)qi * 128 + pos] = packkey(sc, n);
          }
        }
      if (s == 0) loadB(0, tt + 2);
    }
  }
  asm volatile("s_waitcnt lgkmcnt(0)" ::: "memory");
  cntG[((size_t)b * NN + qg * 256 + t) * 2 + chunk] = scnt[t];
}

// ---------------- kNN stage 2: merge 2 chunk survivor lists -> top-20 --------
__global__ __launch_bounds__(256) void knn_merge(const ull* __restrict__ slistG,
    const int* __restrict__ cntG, const _Float16* __restrict__ xh,
    const _Float16* __restrict__ xl, const float* __restrict__ xxg,
    int* __restrict__ idxout, int Cp, int C)
{
  const int lane = threadIdx.x & 63, wave = threadIdx.x >> 6;
  const int b = blockIdx.y;
  const int q = blockIdx.x * 4 + wave;
  const int c0 = cntG[((size_t)b * NN + q) * 2 + 0];
  const int c1 = cntG[((size_t)b * NN + q) * 2 + 1];
  int* op = idxout + ((size_t)b * NN + q) * KK;

  if (c0 <= 64 && c1 <= 64) {
    const ull* s0 = slistG + ((size_t)b * NN + q) * 128;
    const int total = c0 + c1;
    ull e0 = 0, e1 = 0;
    int p0 = lane, p1 = lane + 64;
    if (p0 < total) e0 = (p0 < c0) ? s0[p0] : s0[64 + p0 - c0];
    if (p1 < total) e1 = (p1 < c0) ? s0[p1] : s0[64 + p1 - c0];
    for (int s = 0; s < KK; s++) {
      ull m = e0 > e1 ? e0 : e1;
      ull g = m;
#pragma unroll
      for (int d = 1; d < 64; d <<= 1) { ull o = shflx_u64(g, d); g = o > g ? o : g; }
      if (lane == 0) op[s] = 2047 - (int)(g & 0xFFFFFFFFu);
      if (e0 == g) e0 = 0; else if (e1 == g) e1 = 0;
    }
  } else {
    // exact fallback (survivor cap overflow — expected never): full fp32 rescan
    const _Float16* qh = xh + ((size_t)b * NN + q) * Cp;
    const _Float16* ql = xl + ((size_t)b * NN + q) * Cp;
    const float* xxb = xxg + b * NN;
    float sc[32];
#pragma unroll
    for (int i = 0; i < 32; i++) sc[i] = -0.5f * xxb[lane + 64 * i];
    for (int c = 0; c < C; c++) {
      float qv = (float)qh[c] + (float)ql[c];
      for (int i = 0; i < 32; i++) {
        int n = lane + 64 * i;
        float bv = (float)xh[((size_t)b * NN + n) * Cp + c] + (float)xl[((size_t)b * NN + n) * Cp + c];
        sc[i] = fmaf(qv, bv, sc[i]);
      }
    }
    for (int s = 0; s < KK; s++) {
      ull m = 0; int mi = -1;
      for (int i = 0; i < 32; i++) {
        ull k = packkey(sc[i], lane + 64 * i);
        if (k > m) { m = k; mi = i; }
      }
      ull g = m;
#pragma unroll
      for (int d = 1; d < 64; d <<= 1) { ull o = shflx_u64(g, d); g = o > g ? o : g; }
      if (lane == 0) op[s] = 2047 - (int)(g & 0xFFFFFFFFu);
      if (m == g && mi >= 0) sc[mi] = -3.4e38f;
    }
  }
}

// ---------------- per-layer setup: idx histogram + weight convert (proven r7) --
__global__ __launch_bounds__(256) void setup_kernel(const int* __restrict__ idx,
    int* __restrict__ cnt, const float* __restrict__ w,
    _Float16* __restrict__ wuh, _Float16* __restrict__ wul,
    _Float16* __restrict__ wvh, _Float16* __restrict__ wvl,
    int C, int Cp, int O)
{
  __shared__ int h[2048];
  const int blk = blockIdx.x, t = threadIdx.x;
  if (blk < NB) {
    const int b = blk;
    for (int i = t; i < 2048; i += 256) h[i] = 0;
    __syncthreads();
    const int* ib = idx + (size_t)b * NN * KK;
    for (int i = t; i < NN * KK; i += 256) atomicAdd(&h[ib[i]], 1);
    __syncthreads();
    for (int i = t; i < 2048; i += 256) cnt[b * 2048 + i] = h[i];
  } else {
    int e = (blk - NB) * 256 + t;
    if (e < O * Cp) {
      int o = e / Cp, c = e - o * Cp;
      float a = 0.f, bv = 0.f;
      if (c < C) { a = w[o * 2 * C + c]; bv = w[o * 2 * C + C + c]; }
      float v = bv - a;
      _Float16 ah = (_Float16)a; wuh[e] = ah; wul[e] = (_Float16)(a - (float)ah);
      _Float16 vh = (_Float16)v; wvh[e] = vh; wvl[e] = (_Float16)(v - (float)vh);
    }
  }
}

__global__ __launch_bounds__(256) void w5cvt(const float* __restrict__ w5,
    _Float16* __restrict__ w5h, _Float16* __restrict__ w5l)
{
  int idx = blockIdx.x * 256 + threadIdx.x;
  float v = w5[idx];
  _Float16 h = (_Float16)v;
  w5h[idx] = h;
  w5l[idx] = (_Float16)(v - (float)h);
}

// ---------------- xcat fp32 [b][c][n] -> f16 hi/lo fragments [b][kc][n][32] ----
__global__ __launch_bounds__(256) void y5cvt_kernel(const float* __restrict__ xcat,
    _Float16* __restrict__ xh, _Float16* __restrict__ xl)
{
  const int b = blockIdx.y;
  const int n = blockIdx.x * 256 + threadIdx.x;
  for (int kc = blockIdx.z * 4; kc < blockIdx.z * 4 + 4; kc++) {
    v8h h[4], l[4];
#pragma unroll
    for (int g = 0; g < 4; g++)
#pragma unroll
      for (int j = 0; j < 8; j++) {
        float v = xcat[((size_t)b * 512 + kc * 32 + g * 8 + j) * NN + n];
        _Float16 hh = (_Float16)v;
        h[g][j] = hh;
        l[g][j] = (_Float16)(v - (float)hh);
      }
    size_t base = (((size_t)b * 16 + kc) * NN + n) * 32;
#pragma unroll
    for (int g = 0; g < 4; g++) {
      *(v8h*)(xh + base + g * 8) = h[g];
      *(v8h*)(xl + base + g * 8) = l[g];
    }
  }
}

// ---------------- y5 = w5 * xcat via MFMA (f16 hi/lo 3-product) ----------------
__global__ __launch_bounds__(256) void y5_mfma(const _Float16* __restrict__ w5h,
    const _Float16* __restrict__ w5l, const _Float16* __restrict__ xh,
    const _Float16* __restrict__ xl, float* __restrict__ y5)
{
  const int lane = threadIdx.x & 63, wave = threadIdx.x >> 6;
  const int col = lane & 15, quad = lane >> 4, quad8 = quad * 8;
  const int b = blockIdx.z;
  const int o0 = blockIdx.x * 256 + wave * 64;
  const int nb0 = blockIdx.y * 128;
  v4f acc[4][8];
#pragma unroll
  for (int a = 0; a < 4; a++)
#pragma unroll
    for (int t = 0; t < 8; t++) acc[a][t] = {0.f, 0.f, 0.f, 0.f};

  for (int kc = 0; kc < 16; kc++) {
    v8h Ah[4], Al[4];
#pragma unroll
    for (int a = 0; a < 4; a++) {
      size_t off = (size_t)(o0 + a * 16 + col) * 512 + kc * 32 + quad8;
      Ah[a] = *(const v8h*)(w5h + off);
      Al[a] = *(const v8h*)(w5l + off);
    }
#pragma unroll
    for (int t = 0; t < 8; t++) {
      int n = nb0 + t * 16 + col;
      size_t boff = (((size_t)b * 16 + kc) * NN + n) * 32 + quad8;
      v8h Bh = *(const v8h*)(xh + boff);
      v8h Bl = *(const v8h*)(xl + boff);
#pragma unroll
      for (int a = 0; a < 4; a++) {
        acc[a][t] = __builtin_amdgcn_mfma_f32_16x16x32_f16(Ah[a], Bh, acc[a][t], 0, 0, 0);
        acc[a][t] = __builtin_amdgcn_mfma_f32_16x16x32_f16(Ah[a], Bl, acc[a][t], 0, 0, 0);
        acc[a][t] = __builtin_amdgcn_mfma_f32_16x16x32_f16(Al[a], Bh, acc[a][t], 0, 0, 0);
      }
    }
  }
#pragma unroll
  for (int a = 0; a < 4; a++)
#pragma unroll
    for (int t = 0; t < 8; t++)
#pragma unroll
      for (int j = 0; j < 4; j++)
        y5[((size_t)b * 512 + o0 + a * 16 + quad * 4 + j) * NN + nb0 + t * 16 + col] = acc[a][t][j];
}

// ---------------- U/V chunk (up to 128 out-ch) via MFMA, 4 n-tiles/wave --------
__global__ __launch_bounds__(256) void uv_mfma(const _Float16* __restrict__ wuh,
    const _Float16* __restrict__ wul, const _Float16* __restrict__ wvh,
    const _Float16* __restrict__ wvl, const _Float16* __restrict__ xh,
    const _Float16* __restrict__ xl, float* __restrict__ Uc, float* __restrict__ Vc,
    int Cp, int Och)
{
  const int lane = threadIdx.x & 63, wave = threadIdx.x >> 6;
  const int col = lane & 15, quad = lane >> 4, quad8 = quad * 8;
  const int b = blockIdx.z;
  const int o0 = blockIdx.x * 32;           // chunk-local out channel base
  const int nb0 = blockIdx.y * 256 + wave * 64;
  v4f aU[2][4], aV[2][4];
#pragma unroll
  for (int a = 0; a < 2; a++)
#pragma unroll
    for (int t = 0; t < 4; t++) { aU[a][t] = {0.f,0.f,0.f,0.f}; aV[a][t] = {0.f,0.f,0.f,0.f}; }

  const int KBr = Cp >> 5;
  for (int kb = 0; kb < KBr; kb++) {
    v8h Uh[2], Ul[2], Vh[2], Vl[2];
#pragma unroll
    for (int a = 0; a < 2; a++) {
      size_t off = (size_t)(o0 + a * 16 + col) * Cp + kb * 32 + quad8;
      Uh[a] = *(const v8h*)(wuh + off);
      Ul[a] = *(const v8h*)(wul + off);
      Vh[a] = *(const v8h*)(wvh + off);
      Vl[a] = *(const v8h*)(wvl + off);
    }
#pragma unroll
    for (int t = 0; t < 4; t++) {
      int n = nb0 + t * 16 + col;
      size_t boff = ((size_t)b * NN + n) * Cp + kb * 32 + quad8;
      v8h Bh = *(const v8h*)(xh + boff);
      v8h Bl = *(const v8h*)(xl + boff);
#pragma unroll
      for (int a = 0; a < 2; a++) {
        aU[a][t] = __builtin_amdgcn_mfma_f32_16x16x32_f16(Uh[a], Bh, aU[a][t], 0, 0, 0);
        aU[a][t] = __builtin_amdgcn_mfma_f32_16x16x32_f16(Uh[a], Bl, aU[a][t], 0, 0, 0);
        aU[a][t] = __builtin_amdgcn_mfma_f32_16x16x32_f16(Ul[a], Bh, aU[a][t], 0, 0, 0);
        aV[a][t] = __builtin_amdgcn_mfma_f32_16x16x32_f16(Vh[a], Bh, aV[a][t], 0, 0, 0);
        aV[a][t] = __builtin_amdgcn_mfma_f32_16x16x32_f16(Vh[a], Bl, aV[a][t], 0, 0, 0);
        aV[a][t] = __builtin_amdgcn_mfma_f32_16x16x32_f16(Vl[a], Bh, aV[a][t], 0, 0, 0);
      }
    }
  }
#pragma unroll
  for (int a = 0; a < 2; a++)
#pragma unroll
    for (int t = 0; t < 4; t++)
#pragma unroll
      for (int j = 0; j < 4; j++) {
        size_t base = ((size_t)b * Och + o0 + a * 16 + quad * 4 + j) * NN + nb0 + t * 16 + col;
        Uc[base] = aU[a][t][j];
        Vc[base] = aV[a][t][j];
      }
}

// ---------------- edge6: 2 ch/block, ONE gather pass + closed-form stats -------
// sumY = sG + K*sV ; sumY2 = sum_m cnt[m]*U[m]^2 + 2*sVG + K*sV2  (proven r7/r8)
// max_j y = V[n] + max_j U[idx[n,j]]; leaky-relu commutes with positive scale.
__global__ __launch_bounds__(256) void edge6(const float* __restrict__ Uc,
    const float* __restrict__ Vc, const int* __restrict__ idx,
    const int* __restrict__ cnt, float* __restrict__ xo, int Och)
{
  __shared__ float Ur[2 * 2052];   // +4 pad breaks power-of-2 collisions
  __shared__ float red[10][4];
  __shared__ float smv[4];
  const int b = blockIdx.y, o0 = blockIdx.x * 2;
  const int t = threadIdx.x, lane = t & 63, wave = t >> 6;
  for (int r = 0; r < 2; r++)
    for (int i = t; i < NN; i += 256)
      Ur[r * 2052 + i] = Uc[((size_t)b * Och + o0 + r) * NN + i];
  __syncthreads();
  const float* Vp = Vc + ((size_t)b * Och + o0) * NN;
  const int* ib = idx + (size_t)b * NN * KK;
  const int* cb = cnt + b * NN;

  float sG0 = 0, sG1 = 0, sVG0 = 0, sVG1 = 0, sV0 = 0, sV1 = 0;
  float sV20 = 0, sV21 = 0, sU20 = 0, sU21 = 0;
  float Mr[2][8];
#pragma unroll
  for (int ni = 0; ni < 8; ni++) {
    const int n = t + ni * 256;
    const int* ip = ib + (size_t)n * KK;
    float G0 = 0, G1 = 0;
    float M0 = -3.4e38f, M1 = M0;
#pragma unroll
    for (int j = 0; j < KK; j++) {
      int m = ip[j];
      float u0 = Ur[m], u1 = Ur[2052 + m];
      G0 += u0; M0 = fmaxf(M0, u0);
      G1 += u1; M1 = fmaxf(M1, u1);
    }
    float v0 = Vp[n], v1 = Vp[NN + n];
    sG0 += G0; sVG0 = fmaf(v0, G0, sVG0); sV0 += v0; sV20 = fmaf(v0, v0, sV20);
    sG1 += G1; sVG1 = fmaf(v1, G1, sVG1); sV1 += v1; sV21 = fmaf(v1, v1, sV21);
    Mr[0][ni] = M0; Mr[1][ni] = M1;
  }
  for (int i = t; i < NN; i += 256) {
    float c = (float)cb[i];
    float u0 = Ur[i], u1 = Ur[2052 + i];
    sU20 = fmaf(c * u0, u0, sU20);
    sU21 = fmaf(c * u1, u1, sU21);
  }
  float st[10] = { sG0, sG1, sVG0, sVG1, sV0, sV1, sV20, sV21, sU20, sU21 };
#pragma unroll
  for (int k = 0; k < 10; k++) {
    float a = st[k];
#pragma unroll
    for (int d = 1; d < 64; d <<= 1) a += shflx_f(a, d);
    if (lane == 0) red[k][wave] = a;
  }
  __syncthreads();
  if (t < 2) {
    float g  = red[t][0] + red[t][1] + red[t][2] + red[t][3];
    float vg = red[2 + t][0] + red[2 + t][1] + red[2 + t][2] + red[2 + t][3];
    float v  = red[4 + t][0] + red[4 + t][1] + red[4 + t][2] + red[4 + t][3];
    float v2 = red[6 + t][0] + red[6 + t][1] + red[6 + t][2] + red[6 + t][3];
    float u2 = red[8 + t][0] + red[8 + t][1] + red[8 + t][2] + red[8 + t][3];
    float sumY  = g + (float)KK * v;
    float sumY2 = u2 + 2.f * vg + (float)KK * v2;
    const float inv = 1.f / (float)(NN * KK);
    float mu = sumY * inv;
    float var = fmaxf(sumY2 * inv - mu * mu, 0.f);
    smv[t] = mu;
    smv[2 + t] = rsqrtf(var + EPSF);
  }
  __syncthreads();
  const float mu0 = smv[0], mu1 = smv[1], i0 = smv[2], i1 = smv[3];
#pragma unroll
  for (int ni = 0; ni < 8; ni++) {
    const int n = t + ni * 256;
    float z;
    z = (Mr[0][ni] + Vp[n] - mu0) * i0;
    xo[((size_t)b * 512 + o0 + 0) * NN + n] = z >= 0.f ? z : 0.2f * z;
    z = (Mr[1][ni] + Vp[NN + n] - mu1) * i1;
    xo[((size_t)b * 512 + o0 + 1) * NN + n] = z >= 0.f ? z : 0.2f * z;
  }
}

__global__ __launch_bounds__(256) void bn5stat_kernel(const float* __restrict__ y5,
    float* __restrict__ bn5) {
  __shared__ float rs[4], rq[4];
  const int o = blockIdx.x, t = threadIdx.x, lane = t & 63, wave = t >> 6;
  float s = 0.f, q = 0.f;
  for (int b = 0; b < NB; b++) {
    const float* p = y5 + ((size_t)b * 512 + o) * NN;
    for (int n = t; n < NN; n += 256) { float v = p[n]; s += v; q = fmaf(v, v, q); }
  }
#pragma unroll
  for (int d = 1; d < 64; d <<= 1) { s += shflx_f(s, d); q += shflx_f(q, d); }
  if (lane == 0) { rs[wave] = s; rq[wave] = q; }
  __syncthreads();
  if (t == 0) {
    float S = rs[0] + rs[1] + rs[2] + rs[3];
    float Q = rq[0] + rq[1] + rq[2] + rq[3];
    const float inv = 1.f / (float)(NB * NN);
    float mu = S * inv;
    float var = fmaxf(Q * inv - mu * mu, 0.f);
    bn5[o] = mu;
    bn5[512 + o] = rsqrtf(var + EPSF);
  }
}

__global__ __launch_bounds__(256) void final_kernel(const float* __restrict__ y5,
    const float* __restrict__ bn5, const float* __restrict__ gamma,
    const float* __restrict__ beta, float* __restrict__ out)
{
  __shared__ float rm[4], rs[4];
  const int o = blockIdx.x, b = blockIdx.y, t = threadIdx.x, lane = t & 63, wave = t >> 6;
  const float mu = bn5[o], iv = bn5[512 + o], g = gamma[o], be = beta[o];
  const float* p = y5 + ((size_t)b * 512 + o) * NN;
  float mx = -3.4e38f, sm = 0.f;
  for (int n = t; n < NN; n += 256) {
    float z = (p[n] - mu) * iv;
    z = z * g + be;
    z = (z >= 0.f) ? z : 0.2f * z;
    mx = fmaxf(mx, z);
    sm += z;
  }
#pragma unroll
  for (int d = 1; d < 64; d <<= 1) { mx = fmaxf(mx, shflx_f(mx, d)); sm += shflx_f(sm, d); }
  if (lane == 0) { rm[wave] = mx; rs[wave] = sm; }
  __syncthreads();
  if (t == 0) {
    float M = fmaxf(fmaxf(rm[0], rm[1]), fmaxf(rm[2], rm[3]));
    float S = rs[0] + rs[1] + rs[2] + rs[3];
    out[(size_t)b * 1024 + o] = M;
    out[(size_t)b * 1024 + 512 + o] = S * (1.f / NN);
  }
}

extern "C" void kernel_launch(void* const* d_in, const int* in_sizes, int n_in,
                              void* d_out, int out_size, void* d_ws, size_t ws_size,
                              hipStream_t stream)
{
  (void)in_sizes; (void)n_in; (void)out_size; (void)ws_size;
  const float* x  = (const float*)d_in[0];
  const float* w1 = (const float*)d_in[1];
  const float* w2 = (const float*)d_in[2];
  const float* w3 = (const float*)d_in[3];
  const float* w4 = (const float*)d_in[4];
  const float* w5 = (const float*)d_in[5];
  const float* g5 = (const float*)d_in[6];
  const float* b5 = (const float*)d_in[7];
  float* out = (float*)d_out;

  // workspace layout (same 137 MB footprint)
  float* ws   = (float*)d_ws;
  float* xcat = ws;                         // 16*512*2048 fp32 (67.1 MB)
  float* Ub   = xcat + 16777216;            // 8.39M floats (33.5 MB)
  float* Vb   = Ub + 8388608;               // 8.39M floats (33.5 MB)
  int*   idxb = (int*)(Vb + 8388608);       // 16*2048*20 ints
  float* xxb  = (float*)(idxb + 655360);    // 32768 floats
  float* bn5  = xxb + 32768;                // 1024

  // Vb carve-up: xth | xtl | cntb | weight stash | cnth
  _Float16* xth = (_Float16*)Vb;                       // 4.19M halves
  _Float16* xtl = xth + 4194304;                       // 4.19M halves
  int* cntb = (int*)(Vb + 4194304);                    // 65536 ints
  _Float16* wuh = (_Float16*)(Vb + 4259840);           // 4 x 32768 halves
  _Float16* wul = wuh + 32768;
  _Float16* wvh = wul + 32768;
  _Float16* wvl = wvh + 32768;
  int* cnth = (int*)(Vb + 4325376);                    // 32768 ints

  ull* slist = (ull*)Ub;       // survivor lists alias Ub (dead after merge)
  float* Uc = Ub;              // chunk U (up to 128ch = 4.19M floats)
  float* Vc = Ub + 4194304;    // chunk V (up to 128ch)

  _Float16* w5h = (_Float16*)idxb;   // idx dead after last edge
  _Float16* w5l = w5h + 262144;
  _Float16* xcfh = (_Float16*)Ub;
  _Float16* xcfl = (_Float16*)Vb;
  float* y5 = xcat;

  struct Lyr { const float* xin; long bstride; int C, KB, O, coff; const float* w; };
  const Lyr L[4] = {
    { x,              3L * NN,   3,   1, 64,  0,   w1 },
    { xcat,           512L * NN, 64,  2, 64,  64,  w2 },
    { xcat + 64 * NN, 512L * NN, 64,  2, 128, 128, w3 },
    { xcat + 128 * NN,512L * NN, 128, 4, 256, 256, w4 },
  };

  for (int l = 0; l < 4; l++) {
    const int Cp = L[l].KB * 32, O = L[l].O, C = L[l].C;
    prep_kernel<<<dim3(NN / 256, NB), 256, 0, stream>>>(L[l].xin, xth, xtl, xxb,
                                                        C, L[l].KB, L[l].bstride);
    switch (L[l].KB) {
      case 1: knn2<1><<<dim3(NB * 2, NN / 256), 256, 0, stream>>>(xth, xtl, xxb, slist, cntb); break;
      case 2: knn2<2><<<dim3(NB * 2, NN / 256), 256, 0, stream>>>(xth, xtl, xxb, slist, cntb); break;
      default: knn2<4><<<dim3(NB * 2, NN / 256), 256, 0, stream>>>(xth, xtl, xxb, slist, cntb); break;
    }
    knn_merge<<<dim3(NN / 4, NB), 256, 0, stream>>>(slist, cntb, xth, xtl, xxb, idxb,
                                                    Cp, C);
    const int wblocks = (O * Cp + 255) / 256;
    setup_kernel<<<NB + wblocks, 256, 0, stream>>>(idxb, cnth, L[l].w,
        wuh, wul, wvh, wvl, C, Cp, O);
    for (int c0 = 0; c0 < O; c0 += 128) {
      const int Och = (O - c0) < 128 ? (O - c0) : 128;
      uv_mfma<<<dim3(Och / 32, NN / 256, NB), 256, 0, stream>>>(
          wuh + (size_t)c0 * Cp, wul + (size_t)c0 * Cp,
          wvh + (size_t)c0 * Cp, wvl + (size_t)c0 * Cp,
          xth, xtl, Uc, Vc, Cp, Och);
      edge6<<<dim3(Och / 2, NB), 256, 0, stream>>>(Uc, Vc, idxb, cnth,
          xcat + (size_t)(L[l].coff + c0) * NN, Och);
    }
  }
  w5cvt<<<1024, 256, 0, stream>>>(w5, w5h, w5l);
  y5cvt_kernel<<<dim3(NN / 256, NB, 4), 256, 0, stream>>>(xcat, xcfh, xcfl);
  y5_mfma<<<dim3(2, NN / 128, NB), 256, 0, stream>>>(w5h, w5l, xcfh, xcfl, y5);
  bn5stat_kernel<<<512, 256, 0, stream>>>(y5, bn5);
  final_kernel<<<dim3(512, NB), 256, 0, stream>>>(y5, bn5, g5, b5, out);
}